// Round 13
// baseline (1169.996 us; speedup 1.0000x reference)
//
#include <hip/hip_runtime.h>
#include <cstdint>

#define NROW 66560   // 2*NX + J rows through both MLPs
#define NXP  32768   // nx
#define NV   1024    // J
#define FD   100     // dn output dim
#define GD   28      // input / an output dim
#define HD   300     // hidden dim
#define HP   320     // padded hidden dim
#define SAMP 192     // samples per block (MLP) — R13: 96->192 halves weight traffic
#define NT   12      // sample tiles (16 each)
#define ASTR 328     // LDS activation stride (u16)
#define FKP  128     // f padded K for dist MFMA
#define GKP  32      // g padded K

typedef unsigned short u16;
typedef __bf16 bf16x8 __attribute__((ext_vector_type(8)));
typedef float  f32x4  __attribute__((ext_vector_type(4)));

__device__ inline u16 f2bf(float x) {
  unsigned u = __builtin_bit_cast(unsigned, x);
  unsigned r = (u + 0x7FFF + ((u >> 16) & 1)) >> 16;
  return (u16)r;
}
__device__ inline float bf2f(u16 h) {
  unsigned u = ((unsigned)h) << 16;
  return __builtin_bit_cast(float, u);
}

// ---------------------------------------------------------------------------
// Prep: assemble [X;Y;V] rows, bf16 hi/lo planes (K 28->32) + fp32 copy.
// ---------------------------------------------------------------------------
__global__ __launch_bounds__(256) void prep_x(
    const float* __restrict__ XY, const float* __restrict__ V,
    u16* __restrict__ Xhi, u16* __restrict__ Xlo, float* __restrict__ Xf)
{
  int gid = blockIdx.x * 256 + threadIdx.x;
  int row = gid >> 5, k = gid & 31;
  if (row >= NROW) return;
  float v = 0.f;
  if (k < GD) v = (row < 2 * NXP) ? XY[(size_t)row * GD + k]
                                  : V[(size_t)(row - 2 * NXP) * GD + k];
  u16 hi = f2bf(v);
  u16 lo = f2bf(v - bf2f(hi));
  Xhi[(size_t)row * 32 + k] = hi;
  Xlo[(size_t)row * 32 + k] = lo;
  if (k < GD) Xf[(size_t)row * GD + k] = v;
}

// ---------------------------------------------------------------------------
// Prep: transpose + split + zero-pad all 12 weight matrices. Wt[m][k] layout.
// ---------------------------------------------------------------------------
struct WDesc { const float* W; u16* hi; u16* lo; int K, M, Kpad, Mpad; };
struct WAll  { WDesc d[12]; };

__global__ __launch_bounds__(256) void prep_w(WAll wa)
{
  WDesc d = wa.d[blockIdx.y];
  int gid = blockIdx.x * 256 + threadIdx.x;
  if (gid >= d.Kpad * d.Mpad) return;
  int m = gid / d.Kpad, k = gid - m * d.Kpad;
  float v = (k < d.K && m < d.M) ? d.W[(size_t)k * d.M + m] : 0.f;
  u16 hi = f2bf(v);
  u16 lo = f2bf(v - bf2f(hi));
  d.hi[(size_t)m * d.Kpad + k] = hi;
  d.lo[(size_t)m * d.Kpad + k] = lo;
}

// ---------------------------------------------------------------------------
// Fused 12-layer MLP v9. 192 samples/block, 512 threads (8 waves, 2/SIMD).
// R13: SAMP 96->192 halves weight traffic (347 blocks x 4.9MB = 1.7GB);
// launch_bounds(512,2) -> 256-reg budget so acc f32x4[3][12] (144) + operands
// fit WITHOUT the R12 spill (R12: 128-budget forced 64/64 split, acc=72 > 64
// AGPRs -> 100MB scratch traffic). 1 block/CU (126KB dynamic LDS).
// bf16x2: weights hi/lo split, single bf16 activation plane. Layer 0 keeps
// 3 terms and processes samples in two halves (operand-pressure relief).
// ---------------------------------------------------------------------------
struct BiasAll { const float* b[12]; };

template<int MT>
__device__ __forceinline__ void mm12(
    const u16* __restrict__ Wh, const u16* __restrict__ Wl,
    const u16* aH,
    f32x4 (&acc)[3][NT], int featbase, int m16, int quad)
{
#pragma unroll
  for (int mt = 0; mt < MT; ++mt)
#pragma unroll
    for (int nt = 0; nt < NT; ++nt) acc[mt][nt] = (f32x4)0.f;
#pragma unroll 2
  for (int ch = 0; ch < 10; ++ch) {
    const int k0 = ch * 32 + quad * 8;
    bf16x8 bh[NT];
#pragma unroll
    for (int nt = 0; nt < NT; ++nt)
      bh[nt] = *reinterpret_cast<const bf16x8*>(&aH[(nt * 16 + m16) * ASTR + k0]);
#pragma unroll
    for (int mt = 0; mt < MT; ++mt) {
      size_t wo = (size_t)(featbase + mt * 16) * HP + k0;
      bf16x8 ah = *reinterpret_cast<const bf16x8*>(&Wh[wo]);
      bf16x8 al = *reinterpret_cast<const bf16x8*>(&Wl[wo]);
#pragma unroll
      for (int nt = 0; nt < NT; ++nt) {
        acc[mt][nt] = __builtin_amdgcn_mfma_f32_16x16x32_bf16(ah, bh[nt], acc[mt][nt], 0, 0, 0);
        acc[mt][nt] = __builtin_amdgcn_mfma_f32_16x16x32_bf16(al, bh[nt], acc[mt][nt], 0, 0, 0);
      }
    }
  }
}

// Layer 0/6: K=32, bf16x3 (input lo plane). Two sample-halves to cap operand
// pressure; layer-0 weights (40KB/plane) re-read once — negligible.
template<int MT>
__device__ __forceinline__ void mm12_in(
    const u16* __restrict__ Wh, const u16* __restrict__ Wl,
    const u16* __restrict__ Xhi, const u16* __restrict__ Xlo, int row0,
    f32x4 (&acc)[3][NT], int featbase, int m16, int quad)
{
#pragma unroll
  for (int mt = 0; mt < MT; ++mt)
#pragma unroll
    for (int nt = 0; nt < NT; ++nt) acc[mt][nt] = (f32x4)0.f;
  const int k0 = quad * 8;
#pragma unroll 1
  for (int h = 0; h < 2; ++h) {
    bf16x8 bh[6], bl[6];
#pragma unroll
    for (int nt = 0; nt < 6; ++nt) {
      int samp = (h * 6 + nt) * 16 + m16;
      bh[nt] = *reinterpret_cast<const bf16x8*>(&Xhi[(size_t)(row0 + samp) * 32 + k0]);
      bl[nt] = *reinterpret_cast<const bf16x8*>(&Xlo[(size_t)(row0 + samp) * 32 + k0]);
    }
#pragma unroll
    for (int mt = 0; mt < MT; ++mt) {
      size_t wo = (size_t)(featbase + mt * 16) * 32 + k0;
      bf16x8 ah = *reinterpret_cast<const bf16x8*>(&Wh[wo]);
      bf16x8 al = *reinterpret_cast<const bf16x8*>(&Wl[wo]);
#pragma unroll
      for (int nt = 0; nt < 6; ++nt) {
        acc[mt][h * 6 + nt] = __builtin_amdgcn_mfma_f32_16x16x32_bf16(ah, bh[nt], acc[mt][h * 6 + nt], 0, 0, 0);
        acc[mt][h * 6 + nt] = __builtin_amdgcn_mfma_f32_16x16x32_bf16(al, bh[nt], acc[mt][h * 6 + nt], 0, 0, 0);
        acc[mt][h * 6 + nt] = __builtin_amdgcn_mfma_f32_16x16x32_bf16(ah, bl[nt], acc[mt][h * 6 + nt], 0, 0, 0);
      }
    }
  }
}

template<int MT>
__device__ __forceinline__ void epi12(
    f32x4 (&acc)[3][NT], const float* __restrict__ bias,
    u16* aH, int ftile0, int m16, int quad)
{
#pragma unroll
  for (int mt = 0; mt < MT; ++mt) {
    int featb = ftile0 + mt * 16 + quad * 4;
#pragma unroll
    for (int nt = 0; nt < NT; ++nt) {
      int samp = nt * 16 + m16;
      ushort4 h4;
#pragma unroll
      for (int r = 0; r < 4; ++r) {
        int feat = featb + r;
        float x = acc[mt][nt][r] + (feat < HD ? bias[feat] : 0.f);
        x = fmaxf(x, 0.f);
        reinterpret_cast<u16*>(&h4)[r] = f2bf(x);
      }
      *reinterpret_cast<ushort4*>(&aH[samp * ASTR + featb]) = h4;
    }
  }
}

__global__ __launch_bounds__(512, 2) void mlp_fused(
    const u16* __restrict__ Xhi, const u16* __restrict__ Xlo,
    const float* __restrict__ Xf,
    const u16* __restrict__ Whi, const u16* __restrict__ Wlo,
    BiasAll bp, float* __restrict__ f_all, float* __restrict__ g_all)
{
  extern __shared__ u16 aH[];   // SAMP*ASTR u16 = 125,952 B -> 1 block/CU
  const int tid  = threadIdx.x;
  const int wave = tid >> 6, lane = tid & 63;
  const int m16  = lane & 15, quad = lane >> 4;
  const int row0 = (blockIdx.x * SAMP + SAMP <= NROW) ? blockIdx.x * SAMP
                                                      : NROW - SAMP;  // overlap-safe
  // hidden-layer feature strips: waves 0-3 -> 48 feats, waves 4-7 -> 32 feats
  const int ftile0 = (wave < 4) ? wave * 48 : 192 + (wave - 4) * 32;

  auto W = [&](int s) { return Whi + (size_t)s * HP * HP; };
  auto Lw = [&](int s) { return Wlo + (size_t)s * HP * HP; };

  f32x4 acc[3][NT];

  // ---- dn MLP ----
  if (wave < 4) mm12_in<3>(W(0), Lw(0), Xhi, Xlo, row0, acc, ftile0 + m16, m16, quad);
  else          mm12_in<2>(W(0), Lw(0), Xhi, Xlo, row0, acc, ftile0 + m16, m16, quad);
  if (wave < 4) epi12<3>(acc, bp.b[0], aH, ftile0, m16, quad);
  else          epi12<2>(acc, bp.b[0], aH, ftile0, m16, quad);
  __syncthreads();
#pragma unroll 1
  for (int s = 1; s <= 4; ++s) {
    if (wave < 4) mm12<3>(W(s), Lw(s), aH, acc, ftile0 + m16, m16, quad);
    else          mm12<2>(W(s), Lw(s), aH, acc, ftile0 + m16, m16, quad);
    __syncthreads();
    if (wave < 4) epi12<3>(acc, bp.b[s], aH, ftile0, m16, quad);
    else          epi12<2>(acc, bp.b[s], aH, ftile0, m16, quad);
    __syncthreads();
  }
  // layer 5: FD=100 (pad 128 = 8 tiles), all 8 waves MT=1
  {
    mm12<1>(W(5), Lw(5), aH, acc, wave * 16 + m16, m16, quad);
    const float* b5 = bp.b[5];
    int c = wave * 16 + quad * 4;
    if (c < FD) {
#pragma unroll
      for (int nt = 0; nt < NT; ++nt) {
        int samp = nt * 16 + m16;
        float4 v;
        v.x = acc[0][nt][0] + b5[c + 0];
        v.y = acc[0][nt][1] + b5[c + 1];
        v.z = acc[0][nt][2] + b5[c + 2];
        v.w = acc[0][nt][3] + b5[c + 3];
        *reinterpret_cast<float4*>(&f_all[(size_t)(row0 + samp) * FD + c]) = v;
      }
    }
  }
  __syncthreads();   // layer-5 reads of aH complete before overwrite

  // ---- an MLP ----
  if (wave < 4) mm12_in<3>(W(6), Lw(6), Xhi, Xlo, row0, acc, ftile0 + m16, m16, quad);
  else          mm12_in<2>(W(6), Lw(6), Xhi, Xlo, row0, acc, ftile0 + m16, m16, quad);
  if (wave < 4) epi12<3>(acc, bp.b[6], aH, ftile0, m16, quad);
  else          epi12<2>(acc, bp.b[6], aH, ftile0, m16, quad);
  __syncthreads();
#pragma unroll 1
  for (int s = 7; s <= 10; ++s) {
    if (wave < 4) mm12<3>(W(s), Lw(s), aH, acc, ftile0 + m16, m16, quad);
    else          mm12<2>(W(s), Lw(s), aH, acc, ftile0 + m16, m16, quad);
    __syncthreads();
    if (wave < 4) epi12<3>(acc, bp.b[s], aH, ftile0, m16, quad);
    else          epi12<2>(acc, bp.b[s], aH, ftile0, m16, quad);
    __syncthreads();
  }
  // layer 11: GD=28 (2 tiles), waves 0-1 MT=1
  if (wave < 2) {
    mm12<1>(W(11), Lw(11), aH, acc, wave * 16 + m16, m16, quad);
    const float* b11 = bp.b[11];
    int c = wave * 16 + quad * 4;
    if (c < GD) {
#pragma unroll
      for (int nt = 0; nt < NT; ++nt) {
        int samp = nt * 16 + m16;
        float4 rv = *reinterpret_cast<const float4*>(&Xf[(size_t)(row0 + samp) * GD + c]);
        float4 v;
        v.x = acc[0][nt][0] + b11[c + 0] + rv.x;
        v.y = acc[0][nt][1] + b11[c + 1] + rv.y;
        v.z = acc[0][nt][2] + b11[c + 2] + rv.z;
        v.w = acc[0][nt][3] + b11[c + 3] + rv.w;
        *reinterpret_cast<float4*>(&g_all[(size_t)(row0 + samp) * GD + c]) = v;
      }
    }
  }
}

// ---------------------------------------------------------------------------
// Row squared-norms. One wave per row.
// ---------------------------------------------------------------------------
__global__ __launch_bounds__(256) void norms_k(
    const float* __restrict__ f_all, const float* __restrict__ g_all,
    float* __restrict__ fn, float* __restrict__ gn)
{
  int wave = threadIdx.x >> 6, lane = threadIdx.x & 63;
  int row = blockIdx.x * 4 + wave;
  const float* f = f_all + (size_t)row * FD;
  const float* g = g_all + (size_t)row * GD;
  float s = f[lane] * f[lane];
  if (lane < FD - 64) { float t = f[lane + 64]; s += t * t; }
  float sg = 0.f;
  if (lane < GD) { float t = g[lane]; sg = t * t; }
#pragma unroll
  for (int m = 32; m >= 1; m >>= 1) { s += __shfl_xor(s, m); sg += __shfl_xor(sg, m); }
  if (lane == 0) { fn[row] = s; gn[row] = sg; }
}

// ---------------------------------------------------------------------------
// Prep: split f_all (K 100->128 pad) and g_all (28->32) into bf16 hi/lo.
// ---------------------------------------------------------------------------
__global__ __launch_bounds__(256) void prep_fg(
    const float* __restrict__ f_all, const float* __restrict__ g_all,
    u16* __restrict__ fhi, u16* __restrict__ flo,
    u16* __restrict__ ghi, u16* __restrict__ glo)
{
  size_t gid = (size_t)blockIdx.x * 256 + threadIdx.x;   // NROW * 160
  int row = (int)(gid / 160), t = (int)(gid % 160);
  if (row >= NROW) return;
  if (t < FKP) {
    float v = (t < FD) ? f_all[(size_t)row * FD + t] : 0.f;
    u16 h = f2bf(v);
    fhi[(size_t)row * FKP + t] = h;
    flo[(size_t)row * FKP + t] = f2bf(v - bf2f(h));
  } else {
    int k = t - FKP;
    float v = (k < GD) ? g_all[(size_t)row * GD + k] : 0.f;
    u16 h = f2bf(v);
    ghi[(size_t)row * GKP + k] = h;
    glo[(size_t)row * GKP + k] = f2bf(v - bf2f(h));
  }
}

// ---------------------------------------------------------------------------
// Dist pass via MFMA (unchanged, bf16x3).
// ---------------------------------------------------------------------------
__global__ __launch_bounds__(256) void dist2_k(
    const u16* __restrict__ fhi, const u16* __restrict__ flo,
    const u16* __restrict__ ghi, const u16* __restrict__ glo,
    const float* __restrict__ fn, const float* __restrict__ gn,
    const float* __restrict__ p_eps, const float* __restrict__ p_sig,
    const float* __restrict__ p_sig0, const float* __restrict__ p_cst,
    u16* __restrict__ fm, double* __restrict__ colsum,
    double* __restrict__ ss_parts)
{
  __shared__ float fnX[64], fnY[64], fnV[64], gnX[64], gnY[64], gnV[64];
  __shared__ float red[16][66];
  __shared__ float ssred[4];
  const int tid = threadIdx.x;
  const int w = tid >> 6, lane = tid & 63;
  const int m16 = lane & 15, quad = lane >> 4;
  const int i0 = blockIdx.x * 64, j0 = blockIdx.y * 64;

  if (tid < 64) {
    fnX[tid] = fn[i0 + tid]; fnY[tid] = fn[NXP + i0 + tid]; fnV[tid] = fn[2 * NXP + j0 + tid];
    gnX[tid] = gn[i0 + tid]; gnY[tid] = gn[NXP + i0 + tid]; gnV[tid] = gn[2 * NXP + j0 + tid];
  }

  f32x4 axf[4], ayf[4], axg[4], ayg[4];
#pragma unroll
  for (int nt = 0; nt < 4; ++nt) {
    axf[nt] = (f32x4)0.f; ayf[nt] = (f32x4)0.f;
    axg[nt] = (f32x4)0.f; ayg[nt] = (f32x4)0.f;
  }

  const u16* Xh = fhi + (size_t)(i0 + w * 16 + m16) * FKP;
  const u16* Xl = flo + (size_t)(i0 + w * 16 + m16) * FKP;
  const u16* Yh = fhi + (size_t)(NXP + i0 + w * 16 + m16) * FKP;
  const u16* Yl = flo + (size_t)(NXP + i0 + w * 16 + m16) * FKP;
  const u16* Vh = fhi + (size_t)(2 * NXP + j0) * FKP;
  const u16* Vl = flo + (size_t)(2 * NXP + j0) * FKP;
#pragma unroll 1
  for (int ch = 0; ch < 4; ++ch) {
    const int k = ch * 32 + quad * 8;
    bf16x8 xh = *reinterpret_cast<const bf16x8*>(&Xh[k]);
    bf16x8 xl = *reinterpret_cast<const bf16x8*>(&Xl[k]);
    bf16x8 yh = *reinterpret_cast<const bf16x8*>(&Yh[k]);
    bf16x8 yl = *reinterpret_cast<const bf16x8*>(&Yl[k]);
    bf16x8 vh[4], vl[4];
#pragma unroll
    for (int nt = 0; nt < 4; ++nt) {
      vh[nt] = *reinterpret_cast<const bf16x8*>(&Vh[(size_t)(nt * 16 + m16) * FKP + k]);
      vl[nt] = *reinterpret_cast<const bf16x8*>(&Vl[(size_t)(nt * 16 + m16) * FKP + k]);
    }
    __builtin_amdgcn_sched_barrier(0);
#pragma unroll
    for (int nt = 0; nt < 4; ++nt) {
      axf[nt] = __builtin_amdgcn_mfma_f32_16x16x32_bf16(xh, vh[nt], axf[nt], 0, 0, 0);
      axf[nt] = __builtin_amdgcn_mfma_f32_16x16x32_bf16(xl, vh[nt], axf[nt], 0, 0, 0);
      axf[nt] = __builtin_amdgcn_mfma_f32_16x16x32_bf16(xh, vl[nt], axf[nt], 0, 0, 0);
      ayf[nt] = __builtin_amdgcn_mfma_f32_16x16x32_bf16(yh, vh[nt], ayf[nt], 0, 0, 0);
      ayf[nt] = __builtin_amdgcn_mfma_f32_16x16x32_bf16(yl, vh[nt], ayf[nt], 0, 0, 0);
      ayf[nt] = __builtin_amdgcn_mfma_f32_16x16x32_bf16(yh, vl[nt], ayf[nt], 0, 0, 0);
    }
    __builtin_amdgcn_sched_barrier(0);
  }
  {
    const int k = quad * 8;
    bf16x8 xh = *reinterpret_cast<const bf16x8*>(&ghi[(size_t)(i0 + w * 16 + m16) * GKP + k]);
    bf16x8 xl = *reinterpret_cast<const bf16x8*>(&glo[(size_t)(i0 + w * 16 + m16) * GKP + k]);
    bf16x8 yh = *reinterpret_cast<const bf16x8*>(&ghi[(size_t)(NXP + i0 + w * 16 + m16) * GKP + k]);
    bf16x8 yl = *reinterpret_cast<const bf16x8*>(&glo[(size_t)(NXP + i0 + w * 16 + m16) * GKP + k]);
    bf16x8 vh[4], vl[4];
#pragma unroll
    for (int nt = 0; nt < 4; ++nt) {
      vh[nt] = *reinterpret_cast<const bf16x8*>(&ghi[(size_t)(2 * NXP + j0 + nt * 16 + m16) * GKP + k]);
      vl[nt] = *reinterpret_cast<const bf16x8*>(&glo[(size_t)(2 * NXP + j0 + nt * 16 + m16) * GKP + k]);
    }
    __builtin_amdgcn_sched_barrier(0);
#pragma unroll
    for (int nt = 0; nt < 4; ++nt) {
      axg[nt] = __builtin_amdgcn_mfma_f32_16x16x32_bf16(xh, vh[nt], axg[nt], 0, 0, 0);
      axg[nt] = __builtin_amdgcn_mfma_f32_16x16x32_bf16(xl, vh[nt], axg[nt], 0, 0, 0);
      axg[nt] = __builtin_amdgcn_mfma_f32_16x16x32_bf16(xh, vl[nt], axg[nt], 0, 0, 0);
      ayg[nt] = __builtin_amdgcn_mfma_f32_16x16x32_bf16(yh, vh[nt], ayg[nt], 0, 0, 0);
      ayg[nt] = __builtin_amdgcn_mfma_f32_16x16x32_bf16(yl, vh[nt], ayg[nt], 0, 0, 0);
      ayg[nt] = __builtin_amdgcn_mfma_f32_16x16x32_bf16(yh, vl[nt], ayg[nt], 0, 0, 0);
    }
    __builtin_amdgcn_sched_barrier(0);
  }
  __syncthreads();   // norms ready

  float ep  = 1.f / (1.f + __expf(-p_eps[0]));
  float sg  = p_sig[0] * p_sig[0];
  float sg0 = p_sig0[0] * p_sig0[0];
  float cst = p_cst[0];
  float nis = -1.f / sg, nis0 = -1.f / sg0;
  float omep = 1.f - ep;
  float ss = 0.f;
  float colp[4] = {0.f, 0.f, 0.f, 0.f};
#pragma unroll
  for (int nt = 0; nt < 4; ++nt) {
    float fv = fnV[nt * 16 + m16], gv = gnV[nt * 16 + m16];
#pragma unroll
    for (int r = 0; r < 4; ++r) {
      int il = w * 16 + quad * 4 + r;
      float fx = fnX[il], fy = fnY[il], gx = gnX[il], gy = gnY[il];
      float dxf = fmaxf(fx + fv - 2.f * axf[nt][r], 0.f);
      float dxg = fmaxf(gx + gv - 2.f * axg[nt][r], 0.f);
      float dyf = fmaxf(fy + fv - 2.f * ayf[nt][r], 0.f);
      float dyg = fmaxf(gy + gv - 2.f * ayg[nt][r], 0.f);
      float kx = cst * (omep * __expf(dxf * nis0) + ep) * __expf(dxg * nis);
      float ky = cst * (omep * __expf(dyf * nis0) + ep) * __expf(dyg * nis);
      float fmv = (kx - ky) * 0.03125f;
      fm[(size_t)(i0 + il) * NV + j0 + nt * 16 + m16] = f2bf(fmv);
      ss = fmaf(fmv, fmv, ss);
      colp[nt] += fmv;
    }
  }
#pragma unroll
  for (int m = 32; m >= 1; m >>= 1) ss += __shfl_xor(ss, m);
  if (lane == 0) ssred[w] = ss;
#pragma unroll
  for (int nt = 0; nt < 4; ++nt) red[w * 4 + quad][nt * 16 + m16] = colp[nt];
  __syncthreads();
  if (tid < 64) {
    float s = 0.f;
#pragma unroll
    for (int t = 0; t < 16; ++t) s += red[t][tid];
    atomicAdd(&colsum[j0 + tid], (double)s);
  }
  if (tid == 0) {
    double v = (double)ssred[0] + ssred[1] + ssred[2] + ssred[3];
    atomicAdd(&ss_parts[blockIdx.x & 63], v);
  }
}

// ---------------------------------------------------------------------------
__global__ __launch_bounds__(256) void mu_k(
    const double* __restrict__ colsum, float* __restrict__ mu,
    double* __restrict__ summu2)
{
  __shared__ double wred[4];
  double local = 0.0;
  for (int j = threadIdx.x; j < NV; j += 256) {
    double m = colsum[j] * (1.0 / (double)NXP);
    mu[j] = (float)m;
    local += m * m;
  }
  int lane = threadIdx.x & 63, wave = threadIdx.x >> 6;
#pragma unroll
  for (int m = 32; m >= 1; m >>= 1) local += __shfl_xor(local, m);
  if (lane == 0) wred[wave] = local;
  __syncthreads();
  if (threadIdx.x == 0) *summu2 = wred[0] + wred[1] + wred[2] + wred[3];
}

// ---------------------------------------------------------------------------
// Pass 2 on bf16 fm: z_i = fm[i,:].mu ; sum z^2.
// ---------------------------------------------------------------------------
__global__ __launch_bounds__(256) void pass2_k(
    const u16* __restrict__ fm, const float* __restrict__ mu,
    double* __restrict__ sz_parts)
{
  __shared__ float mus[NV];
  for (int l = threadIdx.x; l < NV; l += 256) mus[l] = mu[l];
  __syncthreads();
  __shared__ double zb[4];
  int wave = threadIdx.x >> 6, lane = threadIdx.x & 63;
  int row = blockIdx.x * 4 + wave;
  const u16* frow = fm + (size_t)row * NV;
  float z = 0.f;
#pragma unroll
  for (int it = 0; it < 2; ++it) {
    int base = (lane + 64 * it) * 8;
    uint4 raw = *reinterpret_cast<const uint4*>(&frow[base]);
    const u16* v = reinterpret_cast<const u16*>(&raw);
#pragma unroll
    for (int k = 0; k < 8; ++k) z = fmaf(bf2f(v[k]), mus[base + k], z);
  }
#pragma unroll
  for (int m = 32; m >= 1; m >>= 1) z += __shfl_xor(z, m);
  if (lane == 0) zb[wave] = (double)z * (double)z;
  __syncthreads();
  if (threadIdx.x == 0)
    atomicAdd(&sz_parts[blockIdx.x & 63], zb[0] + zb[1] + zb[2] + zb[3]);
}

__global__ __launch_bounds__(64) void final_k(
    const double* __restrict__ ss_parts, const double* __restrict__ sz_parts,
    const double* __restrict__ summu2, float* __restrict__ out)
{
  int lane = threadIdx.x;
  double ss = ss_parts[lane], sz = sz_parts[lane];
#pragma unroll
  for (int m = 32; m >= 1; m >>= 1) { ss += __shfl_xor(ss, m); sz += __shfl_xor(sz, m); }
  if (lane == 0) {
    double smu2 = *summu2;
    const double nx = (double)NXP;
    double t1 = smu2 * nx / (nx - 1.0);
    double t2 = ss / (nx * (nx - 1.0));
    double um = t1 - t2;
    double uv = 4.0 * (sz / nx) - 4.0 * smu2 * smu2;
    out[0] = (float)(-(um / sqrt(uv + 1e-6)));
  }
}

// ---------------------------------------------------------------------------
extern "C" void kernel_launch(void* const* d_in, const int* in_sizes, int n_in,
                              void* d_out, int out_size, void* d_ws, size_t ws_size,
                              hipStream_t stream)
{
  (void)in_sizes; (void)n_in; (void)out_size; (void)ws_size;
  const float* XY = (const float*)d_in[0];
  const float* V  = (const float*)d_in[1];
  const float* dnW[6]; const float* dnb[6]; const float* anW[6]; const float* anb[6];
  for (int i = 0; i < 6; ++i) {
    dnW[i] = (const float*)d_in[2 + 2 * i];  dnb[i] = (const float*)d_in[3 + 2 * i];
    anW[i] = (const float*)d_in[14 + 2 * i]; anb[i] = (const float*)d_in[15 + 2 * i];
  }
  const float* p_eps  = (const float*)d_in[26];
  const float* p_sig  = (const float*)d_in[27];
  const float* p_sig0 = (const float*)d_in[28];
  const float* p_cst  = (const float*)d_in[29];

  char* base = (char*)d_ws;
  size_t off = 0;
  auto alloc = [&](size_t b) { size_t o = off; off += (b + 255) & ~(size_t)255; return o; };
  float* Xf    = (float*)(base + alloc((size_t)NROW * GD * 4));
  u16*   Xhi   = (u16*)  (base + alloc((size_t)NROW * 32 * 2));
  u16*   Xlo   = (u16*)  (base + alloc((size_t)NROW * 32 * 2));
  float* f_all = (float*)(base + alloc((size_t)NROW * FD * 4));
  float* g_all = (float*)(base + alloc((size_t)NROW * GD * 4));
  float* fn    = (float*)(base + alloc((size_t)NROW * 4));
  float* gn    = (float*)(base + alloc((size_t)NROW * 4));
  float* mu    = (float*)(base + alloc((size_t)NV * 4));
  size_t zoff = off;
  double* colsum   = (double*)(base + alloc(NV * 8));
  double* ss_parts = (double*)(base + alloc(64 * 8));
  double* sz_parts = (double*)(base + alloc(64 * 8));
  double* summu2   = (double*)(base + alloc(8));
  size_t zbytes = off - zoff;
  u16* Whi = (u16*)(base + alloc((size_t)12 * HP * HP * 2));
  u16* Wlo = (u16*)(base + alloc((size_t)12 * HP * HP * 2));
  u16* fhi = (u16*)(base + alloc((size_t)NROW * FKP * 2));
  u16* flo = (u16*)(base + alloc((size_t)NROW * FKP * 2));
  u16* ghi = (u16*)(base + alloc((size_t)NROW * GKP * 2));
  u16* glo = (u16*)(base + alloc((size_t)NROW * GKP * 2));
  u16* fm  = (u16*)(base + alloc((size_t)NXP * NV * 2));   // bf16 fm

  hipMemsetAsync(base + zoff, 0, zbytes, stream);

  dim3 blk(256);
  prep_x<<<NROW * 32 / 256, blk, 0, stream>>>(XY, V, Xhi, Xlo, Xf);

  WAll wa;
  for (int i = 0; i < 6; ++i) {
    int K = (i == 0) ? GD : HD, M = (i == 5) ? FD : HD;
    int Kp = (i == 0) ? 32 : HP, Mp = (i == 5) ? 128 : HP;
    wa.d[i] = {dnW[i], Whi + (size_t)i * HP * HP, Wlo + (size_t)i * HP * HP, K, M, Kp, Mp};
  }
  for (int i = 0; i < 6; ++i) {
    int K = (i == 0) ? GD : HD, M = (i == 5) ? GD : HD;
    int Kp = (i == 0) ? 32 : HP, Mp = (i == 5) ? 64 : HP;
    wa.d[6 + i] = {anW[i], Whi + (size_t)(6 + i) * HP * HP, Wlo + (size_t)(6 + i) * HP * HP, K, M, Kp, Mp};
  }
  prep_w<<<dim3((HP * HP + 255) / 256, 12), blk, 0, stream>>>(wa);

  BiasAll bp;
  for (int i = 0; i < 6; ++i) { bp.b[i] = dnb[i]; bp.b[6 + i] = anb[i]; }

  const size_t lds_bytes = (size_t)SAMP * ASTR * sizeof(u16);  // 125,952
  hipFuncSetAttribute(reinterpret_cast<const void*>(&mlp_fused),
                      hipFuncAttributeMaxDynamicSharedMemorySize, (int)lds_bytes);
  const int nblk = (NROW + SAMP - 1) / SAMP;   // 347, last block overlaps (idempotent)
  mlp_fused<<<nblk, dim3(512), lds_bytes, stream>>>(
      Xhi, Xlo, Xf, Whi, Wlo, bp, f_all, g_all);

  norms_k<<<NROW / 4, blk, 0, stream>>>(f_all, g_all, fn, gn);
  prep_fg<<<(int)(((size_t)NROW * 160 + 255) / 256), blk, 0, stream>>>(
      f_all, g_all, fhi, flo, ghi, glo);
  dist2_k<<<dim3(NXP / 64, NV / 64), blk, 0, stream>>>(
      fhi, flo, ghi, glo, fn, gn, p_eps, p_sig, p_sig0, p_cst,
      fm, colsum, ss_parts);
  mu_k<<<1, blk, 0, stream>>>(colsum, mu, summu2);
  pass2_k<<<NXP / 4, blk, 0, stream>>>(fm, mu, sz_parts);
  final_k<<<1, 64, 0, stream>>>(ss_parts, sz_parts, summu2, (float*)d_out);
}

// Round 14
// 794.231 us; speedup vs baseline: 1.4731x; 1.4731x over previous
//
#include <hip/hip_runtime.h>
#include <cstdint>

#define NROW 66560   // 2*NX + J rows through both MLPs
#define NXP  32768   // nx
#define NV   1024    // J
#define FD   100     // dn output dim
#define GD   28      // input / an output dim
#define HD   300     // hidden dim
#define HP   320     // padded hidden dim
#define SAMP 96      // samples per block (MLP)
#define NT   6       // sample tiles
#define ASTR 328     // LDS activation stride (u16)
#define FKP  128     // f padded K for dist MFMA
#define GKP  32      // g padded K

typedef unsigned short u16;
typedef __bf16 bf16x8 __attribute__((ext_vector_type(8)));
typedef float  f32x4  __attribute__((ext_vector_type(4)));

__device__ inline u16 f2bf(float x) {
  unsigned u = __builtin_bit_cast(unsigned, x);
  unsigned r = (u + 0x7FFF + ((u >> 16) & 1)) >> 16;
  return (u16)r;
}
__device__ inline float bf2f(u16 h) {
  unsigned u = ((unsigned)h) << 16;
  return __builtin_bit_cast(float, u);
}

// ---------------------------------------------------------------------------
// Prep: assemble [X;Y;V] rows -> single bf16 plane (K 28->32) + fp32 copy.
// (input-lo plane dropped in R14: same 2^-9 magnitude as the validated
//  activation quantization)
// ---------------------------------------------------------------------------
__global__ __launch_bounds__(256) void prep_x(
    const float* __restrict__ XY, const float* __restrict__ V,
    u16* __restrict__ Xhi, float* __restrict__ Xf)
{
  int gid = blockIdx.x * 256 + threadIdx.x;
  int row = gid >> 5, k = gid & 31;
  if (row >= NROW) return;
  float v = 0.f;
  if (k < GD) v = (row < 2 * NXP) ? XY[(size_t)row * GD + k]
                                  : V[(size_t)(row - 2 * NXP) * GD + k];
  Xhi[(size_t)row * 32 + k] = f2bf(v);
  if (k < GD) Xf[(size_t)row * GD + k] = v;
}

// ---------------------------------------------------------------------------
// Prep: transpose + split + zero-pad all 12 weight matrices. Wt[m][k] layout.
// ---------------------------------------------------------------------------
struct WDesc { const float* W; u16* hi; u16* lo; int K, M, Kpad, Mpad; };
struct WAll  { WDesc d[12]; };

__global__ __launch_bounds__(256) void prep_w(WAll wa)
{
  WDesc d = wa.d[blockIdx.y];
  int gid = blockIdx.x * 256 + threadIdx.x;
  if (gid >= d.Kpad * d.Mpad) return;
  int m = gid / d.Kpad, k = gid - m * d.Kpad;
  float v = (k < d.K && m < d.M) ? d.W[(size_t)k * d.M + m] : 0.f;
  u16 hi = f2bf(v);
  u16 lo = f2bf(v - bf2f(hi));
  d.hi[(size_t)m * d.Kpad + k] = hi;
  d.lo[(size_t)m * d.Kpad + k] = lo;
}

// ---------------------------------------------------------------------------
// Fused 12-layer MLP v10 = R12 shape (96 samp, 512 thr, 4 waves/SIMD,
// 63KB LDS -> 2 blocks/CU) with the spill surgically removed:
//  - layer 0/6 now bf16x2 (input single-bf16) -> kills the bl[6] 24-reg spike
//  - hidden chunks: weights batched once (wh/wl[MT]), B-frags in two halves
//    of 3 -> peak ~124 regs <= 128 budget.
// bf16x2: weights hi/lo split (full precision), activations single bf16.
// ---------------------------------------------------------------------------
struct BiasAll { const float* b[12]; };

template<int MT>
__device__ __forceinline__ void mm6(
    const u16* __restrict__ Wh, const u16* __restrict__ Wl,
    const u16* aH,
    f32x4 (&acc)[3][NT], int featbase, int m16, int quad)
{
#pragma unroll
  for (int mt = 0; mt < MT; ++mt)
#pragma unroll
    for (int nt = 0; nt < NT; ++nt) acc[mt][nt] = (f32x4)0.f;
#pragma unroll 2
  for (int ch = 0; ch < 10; ++ch) {
    const int k0 = ch * 32 + quad * 8;
    bf16x8 wh[MT], wl[MT];
#pragma unroll
    for (int mt = 0; mt < MT; ++mt) {
      size_t wo = (size_t)(featbase + mt * 16) * HP + k0;
      wh[mt] = *reinterpret_cast<const bf16x8*>(&Wh[wo]);
      wl[mt] = *reinterpret_cast<const bf16x8*>(&Wl[wo]);
    }
#pragma unroll
    for (int g = 0; g < 2; ++g) {
      bf16x8 bh[3];
#pragma unroll
      for (int n3 = 0; n3 < 3; ++n3)
        bh[n3] = *reinterpret_cast<const bf16x8*>(&aH[((g * 3 + n3) * 16 + m16) * ASTR + k0]);
#pragma unroll
      for (int mt = 0; mt < MT; ++mt)
#pragma unroll
        for (int n3 = 0; n3 < 3; ++n3) {
          acc[mt][g * 3 + n3] = __builtin_amdgcn_mfma_f32_16x16x32_bf16(wh[mt], bh[n3], acc[mt][g * 3 + n3], 0, 0, 0);
          acc[mt][g * 3 + n3] = __builtin_amdgcn_mfma_f32_16x16x32_bf16(wl[mt], bh[n3], acc[mt][g * 3 + n3], 0, 0, 0);
        }
    }
  }
}

// Layer 0/6: K=32, bf16x2, input single-bf16 plane.
template<int MT>
__device__ __forceinline__ void mm6_in(
    const u16* __restrict__ Wh, const u16* __restrict__ Wl,
    const u16* __restrict__ Xhi, int row0,
    f32x4 (&acc)[3][NT], int featbase, int m16, int quad)
{
#pragma unroll
  for (int mt = 0; mt < MT; ++mt)
#pragma unroll
    for (int nt = 0; nt < NT; ++nt) acc[mt][nt] = (f32x4)0.f;
  const int k0 = quad * 8;
  bf16x8 wh[MT], wl[MT];
#pragma unroll
  for (int mt = 0; mt < MT; ++mt) {
    size_t wo = (size_t)(featbase + mt * 16) * 32 + k0;
    wh[mt] = *reinterpret_cast<const bf16x8*>(&Wh[wo]);
    wl[mt] = *reinterpret_cast<const bf16x8*>(&Wl[wo]);
  }
#pragma unroll
  for (int g = 0; g < 2; ++g) {
    bf16x8 bh[3];
#pragma unroll
    for (int n3 = 0; n3 < 3; ++n3) {
      int samp = (g * 3 + n3) * 16 + m16;
      bh[n3] = *reinterpret_cast<const bf16x8*>(&Xhi[(size_t)(row0 + samp) * 32 + k0]);
    }
#pragma unroll
    for (int mt = 0; mt < MT; ++mt)
#pragma unroll
      for (int n3 = 0; n3 < 3; ++n3) {
        acc[mt][g * 3 + n3] = __builtin_amdgcn_mfma_f32_16x16x32_bf16(wh[mt], bh[n3], acc[mt][g * 3 + n3], 0, 0, 0);
        acc[mt][g * 3 + n3] = __builtin_amdgcn_mfma_f32_16x16x32_bf16(wl[mt], bh[n3], acc[mt][g * 3 + n3], 0, 0, 0);
      }
  }
}

template<int MT>
__device__ __forceinline__ void epi6(
    f32x4 (&acc)[3][NT], const float* __restrict__ bias,
    u16* aH, int ftile0, int m16, int quad)
{
#pragma unroll
  for (int mt = 0; mt < MT; ++mt) {
    int featb = ftile0 + mt * 16 + quad * 4;
#pragma unroll
    for (int nt = 0; nt < NT; ++nt) {
      int samp = nt * 16 + m16;
      ushort4 h4;
#pragma unroll
      for (int r = 0; r < 4; ++r) {
        int feat = featb + r;
        float x = acc[mt][nt][r] + (feat < HD ? bias[feat] : 0.f);
        x = fmaxf(x, 0.f);
        reinterpret_cast<u16*>(&h4)[r] = f2bf(x);
      }
      *reinterpret_cast<ushort4*>(&aH[samp * ASTR + featb]) = h4;
    }
  }
}

__global__ __launch_bounds__(512, 4) void mlp_fused(
    const u16* __restrict__ Xhi, const float* __restrict__ Xf,
    const u16* __restrict__ Whi, const u16* __restrict__ Wlo,
    BiasAll bp, float* __restrict__ f_all, float* __restrict__ g_all)
{
  __shared__ u16 aH[SAMP * ASTR];   // 62,976 B -> 2 blocks/CU
  const int tid  = threadIdx.x;
  const int wave = tid >> 6, lane = tid & 63;
  const int m16  = lane & 15, quad = lane >> 4;
  const int row0 = (blockIdx.x * SAMP + SAMP <= NROW) ? blockIdx.x * SAMP
                                                      : NROW - SAMP;  // overlap-safe
  // hidden-layer feature strips: waves 0-3 -> 48 feats, waves 4-7 -> 32 feats
  const int ftile0 = (wave < 4) ? wave * 48 : 192 + (wave - 4) * 32;

  auto W = [&](int s) { return Whi + (size_t)s * HP * HP; };
  auto Lw = [&](int s) { return Wlo + (size_t)s * HP * HP; };

  f32x4 acc[3][NT];

  // ---- dn MLP ----
  if (wave < 4) mm6_in<3>(W(0), Lw(0), Xhi, row0, acc, ftile0 + m16, m16, quad);
  else          mm6_in<2>(W(0), Lw(0), Xhi, row0, acc, ftile0 + m16, m16, quad);
  if (wave < 4) epi6<3>(acc, bp.b[0], aH, ftile0, m16, quad);
  else          epi6<2>(acc, bp.b[0], aH, ftile0, m16, quad);
  __syncthreads();
#pragma unroll 1
  for (int s = 1; s <= 4; ++s) {
    if (wave < 4) mm6<3>(W(s), Lw(s), aH, acc, ftile0 + m16, m16, quad);
    else          mm6<2>(W(s), Lw(s), aH, acc, ftile0 + m16, m16, quad);
    __syncthreads();
    if (wave < 4) epi6<3>(acc, bp.b[s], aH, ftile0, m16, quad);
    else          epi6<2>(acc, bp.b[s], aH, ftile0, m16, quad);
    __syncthreads();
  }
  // layer 5: FD=100 (pad 128 = 8 tiles), all 8 waves MT=1
  {
    mm6<1>(W(5), Lw(5), aH, acc, wave * 16 + m16, m16, quad);
    const float* b5 = bp.b[5];
    int c = wave * 16 + quad * 4;
    if (c < FD) {
#pragma unroll
      for (int nt = 0; nt < NT; ++nt) {
        int samp = nt * 16 + m16;
        float4 v;
        v.x = acc[0][nt][0] + b5[c + 0];
        v.y = acc[0][nt][1] + b5[c + 1];
        v.z = acc[0][nt][2] + b5[c + 2];
        v.w = acc[0][nt][3] + b5[c + 3];
        *reinterpret_cast<float4*>(&f_all[(size_t)(row0 + samp) * FD + c]) = v;
      }
    }
  }
  __syncthreads();   // layer-5 reads of aH complete before overwrite

  // ---- an MLP ----
  if (wave < 4) mm6_in<3>(W(6), Lw(6), Xhi, row0, acc, ftile0 + m16, m16, quad);
  else          mm6_in<2>(W(6), Lw(6), Xhi, row0, acc, ftile0 + m16, m16, quad);
  if (wave < 4) epi6<3>(acc, bp.b[6], aH, ftile0, m16, quad);
  else          epi6<2>(acc, bp.b[6], aH, ftile0, m16, quad);
  __syncthreads();
#pragma unroll 1
  for (int s = 7; s <= 10; ++s) {
    if (wave < 4) mm6<3>(W(s), Lw(s), aH, acc, ftile0 + m16, m16, quad);
    else          mm6<2>(W(s), Lw(s), aH, acc, ftile0 + m16, m16, quad);
    __syncthreads();
    if (wave < 4) epi6<3>(acc, bp.b[s], aH, ftile0, m16, quad);
    else          epi6<2>(acc, bp.b[s], aH, ftile0, m16, quad);
    __syncthreads();
  }
  // layer 11: GD=28 (2 tiles), waves 0-1 MT=1
  if (wave < 2) {
    mm6<1>(W(11), Lw(11), aH, acc, wave * 16 + m16, m16, quad);
    const float* b11 = bp.b[11];
    int c = wave * 16 + quad * 4;
    if (c < GD) {
#pragma unroll
      for (int nt = 0; nt < NT; ++nt) {
        int samp = nt * 16 + m16;
        float4 rv = *reinterpret_cast<const float4*>(&Xf[(size_t)(row0 + samp) * GD + c]);
        float4 v;
        v.x = acc[0][nt][0] + b11[c + 0] + rv.x;
        v.y = acc[0][nt][1] + b11[c + 1] + rv.y;
        v.z = acc[0][nt][2] + b11[c + 2] + rv.z;
        v.w = acc[0][nt][3] + b11[c + 3] + rv.w;
        *reinterpret_cast<float4*>(&g_all[(size_t)(row0 + samp) * GD + c]) = v;
      }
    }
  }
}

// ---------------------------------------------------------------------------
// Row squared-norms. One wave per row.
// ---------------------------------------------------------------------------
__global__ __launch_bounds__(256) void norms_k(
    const float* __restrict__ f_all, const float* __restrict__ g_all,
    float* __restrict__ fn, float* __restrict__ gn)
{
  int wave = threadIdx.x >> 6, lane = threadIdx.x & 63;
  int row = blockIdx.x * 4 + wave;
  const float* f = f_all + (size_t)row * FD;
  const float* g = g_all + (size_t)row * GD;
  float s = f[lane] * f[lane];
  if (lane < FD - 64) { float t = f[lane + 64]; s += t * t; }
  float sg = 0.f;
  if (lane < GD) { float t = g[lane]; sg = t * t; }
#pragma unroll
  for (int m = 32; m >= 1; m >>= 1) { s += __shfl_xor(s, m); sg += __shfl_xor(sg, m); }
  if (lane == 0) { fn[row] = s; gn[row] = sg; }
}

// ---------------------------------------------------------------------------
// Prep: split f_all (K 100->128 pad) and g_all (28->32) into bf16 hi/lo.
// ---------------------------------------------------------------------------
__global__ __launch_bounds__(256) void prep_fg(
    const float* __restrict__ f_all, const float* __restrict__ g_all,
    u16* __restrict__ fhi, u16* __restrict__ flo,
    u16* __restrict__ ghi, u16* __restrict__ glo)
{
  size_t gid = (size_t)blockIdx.x * 256 + threadIdx.x;   // NROW * 160
  int row = (int)(gid / 160), t = (int)(gid % 160);
  if (row >= NROW) return;
  if (t < FKP) {
    float v = (t < FD) ? f_all[(size_t)row * FD + t] : 0.f;
    u16 h = f2bf(v);
    fhi[(size_t)row * FKP + t] = h;
    flo[(size_t)row * FKP + t] = f2bf(v - bf2f(h));
  } else {
    int k = t - FKP;
    float v = (k < GD) ? g_all[(size_t)row * GD + k] : 0.f;
    u16 h = f2bf(v);
    ghi[(size_t)row * GKP + k] = h;
    glo[(size_t)row * GKP + k] = f2bf(v - bf2f(h));
  }
}

// ---------------------------------------------------------------------------
// Dist pass via MFMA (unchanged, bf16x3).
// ---------------------------------------------------------------------------
__global__ __launch_bounds__(256) void dist2_k(
    const u16* __restrict__ fhi, const u16* __restrict__ flo,
    const u16* __restrict__ ghi, const u16* __restrict__ glo,
    const float* __restrict__ fn, const float* __restrict__ gn,
    const float* __restrict__ p_eps, const float* __restrict__ p_sig,
    const float* __restrict__ p_sig0, const float* __restrict__ p_cst,
    u16* __restrict__ fm, double* __restrict__ colsum,
    double* __restrict__ ss_parts)
{
  __shared__ float fnX[64], fnY[64], fnV[64], gnX[64], gnY[64], gnV[64];
  __shared__ float red[16][66];
  __shared__ float ssred[4];
  const int tid = threadIdx.x;
  const int w = tid >> 6, lane = tid & 63;
  const int m16 = lane & 15, quad = lane >> 4;
  const int i0 = blockIdx.x * 64, j0 = blockIdx.y * 64;

  if (tid < 64) {
    fnX[tid] = fn[i0 + tid]; fnY[tid] = fn[NXP + i0 + tid]; fnV[tid] = fn[2 * NXP + j0 + tid];
    gnX[tid] = gn[i0 + tid]; gnY[tid] = gn[NXP + i0 + tid]; gnV[tid] = gn[2 * NXP + j0 + tid];
  }

  f32x4 axf[4], ayf[4], axg[4], ayg[4];
#pragma unroll
  for (int nt = 0; nt < 4; ++nt) {
    axf[nt] = (f32x4)0.f; ayf[nt] = (f32x4)0.f;
    axg[nt] = (f32x4)0.f; ayg[nt] = (f32x4)0.f;
  }

  const u16* Xh = fhi + (size_t)(i0 + w * 16 + m16) * FKP;
  const u16* Xl = flo + (size_t)(i0 + w * 16 + m16) * FKP;
  const u16* Yh = fhi + (size_t)(NXP + i0 + w * 16 + m16) * FKP;
  const u16* Yl = flo + (size_t)(NXP + i0 + w * 16 + m16) * FKP;
  const u16* Vh = fhi + (size_t)(2 * NXP + j0) * FKP;
  const u16* Vl = flo + (size_t)(2 * NXP + j0) * FKP;
#pragma unroll 1
  for (int ch = 0; ch < 4; ++ch) {
    const int k = ch * 32 + quad * 8;
    bf16x8 xh = *reinterpret_cast<const bf16x8*>(&Xh[k]);
    bf16x8 xl = *reinterpret_cast<const bf16x8*>(&Xl[k]);
    bf16x8 yh = *reinterpret_cast<const bf16x8*>(&Yh[k]);
    bf16x8 yl = *reinterpret_cast<const bf16x8*>(&Yl[k]);
    bf16x8 vh[4], vl[4];
#pragma unroll
    for (int nt = 0; nt < 4; ++nt) {
      vh[nt] = *reinterpret_cast<const bf16x8*>(&Vh[(size_t)(nt * 16 + m16) * FKP + k]);
      vl[nt] = *reinterpret_cast<const bf16x8*>(&Vl[(size_t)(nt * 16 + m16) * FKP + k]);
    }
    __builtin_amdgcn_sched_barrier(0);
#pragma unroll
    for (int nt = 0; nt < 4; ++nt) {
      axf[nt] = __builtin_amdgcn_mfma_f32_16x16x32_bf16(xh, vh[nt], axf[nt], 0, 0, 0);
      axf[nt] = __builtin_amdgcn_mfma_f32_16x16x32_bf16(xl, vh[nt], axf[nt], 0, 0, 0);
      axf[nt] = __builtin_amdgcn_mfma_f32_16x16x32_bf16(xh, vl[nt], axf[nt], 0, 0, 0);
      ayf[nt] = __builtin_amdgcn_mfma_f32_16x16x32_bf16(yh, vh[nt], ayf[nt], 0, 0, 0);
      ayf[nt] = __builtin_amdgcn_mfma_f32_16x16x32_bf16(yl, vh[nt], ayf[nt], 0, 0, 0);
      ayf[nt] = __builtin_amdgcn_mfma_f32_16x16x32_bf16(yh, vl[nt], ayf[nt], 0, 0, 0);
    }
    __builtin_amdgcn_sched_barrier(0);
  }
  {
    const int k = quad * 8;
    bf16x8 xh = *reinterpret_cast<const bf16x8*>(&ghi[(size_t)(i0 + w * 16 + m16) * GKP + k]);
    bf16x8 xl = *reinterpret_cast<const bf16x8*>(&glo[(size_t)(i0 + w * 16 + m16) * GKP + k]);
    bf16x8 yh = *reinterpret_cast<const bf16x8*>(&ghi[(size_t)(NXP + i0 + w * 16 + m16) * GKP + k]);
    bf16x8 yl = *reinterpret_cast<const bf16x8*>(&glo[(size_t)(NXP + i0 + w * 16 + m16) * GKP + k]);
    bf16x8 vh[4], vl[4];
#pragma unroll
    for (int nt = 0; nt < 4; ++nt) {
      vh[nt] = *reinterpret_cast<const bf16x8*>(&ghi[(size_t)(2 * NXP + j0 + nt * 16 + m16) * GKP + k]);
      vl[nt] = *reinterpret_cast<const bf16x8*>(&glo[(size_t)(2 * NXP + j0 + nt * 16 + m16) * GKP + k]);
    }
    __builtin_amdgcn_sched_barrier(0);
#pragma unroll
    for (int nt = 0; nt < 4; ++nt) {
      axg[nt] = __builtin_amdgcn_mfma_f32_16x16x32_bf16(xh, vh[nt], axg[nt], 0, 0, 0);
      axg[nt] = __builtin_amdgcn_mfma_f32_16x16x32_bf16(xl, vh[nt], axg[nt], 0, 0, 0);
      axg[nt] = __builtin_amdgcn_mfma_f32_16x16x32_bf16(xh, vl[nt], axg[nt], 0, 0, 0);
      ayg[nt] = __builtin_amdgcn_mfma_f32_16x16x32_bf16(yh, vh[nt], ayg[nt], 0, 0, 0);
      ayg[nt] = __builtin_amdgcn_mfma_f32_16x16x32_bf16(yl, vh[nt], ayg[nt], 0, 0, 0);
      ayg[nt] = __builtin_amdgcn_mfma_f32_16x16x32_bf16(yh, vl[nt], ayg[nt], 0, 0, 0);
    }
    __builtin_amdgcn_sched_barrier(0);
  }
  __syncthreads();   // norms ready

  float ep  = 1.f / (1.f + __expf(-p_eps[0]));
  float sg  = p_sig[0] * p_sig[0];
  float sg0 = p_sig0[0] * p_sig0[0];
  float cst = p_cst[0];
  float nis = -1.f / sg, nis0 = -1.f / sg0;
  float omep = 1.f - ep;
  float ss = 0.f;
  float colp[4] = {0.f, 0.f, 0.f, 0.f};
#pragma unroll
  for (int nt = 0; nt < 4; ++nt) {
    float fv = fnV[nt * 16 + m16], gv = gnV[nt * 16 + m16];
#pragma unroll
    for (int r = 0; r < 4; ++r) {
      int il = w * 16 + quad * 4 + r;
      float fx = fnX[il], fy = fnY[il], gx = gnX[il], gy = gnY[il];
      float dxf = fmaxf(fx + fv - 2.f * axf[nt][r], 0.f);
      float dxg = fmaxf(gx + gv - 2.f * axg[nt][r], 0.f);
      float dyf = fmaxf(fy + fv - 2.f * ayf[nt][r], 0.f);
      float dyg = fmaxf(gy + gv - 2.f * ayg[nt][r], 0.f);
      float kx = cst * (omep * __expf(dxf * nis0) + ep) * __expf(dxg * nis);
      float ky = cst * (omep * __expf(dyf * nis0) + ep) * __expf(dyg * nis);
      float fmv = (kx - ky) * 0.03125f;
      fm[(size_t)(i0 + il) * NV + j0 + nt * 16 + m16] = f2bf(fmv);
      ss = fmaf(fmv, fmv, ss);
      colp[nt] += fmv;
    }
  }
#pragma unroll
  for (int m = 32; m >= 1; m >>= 1) ss += __shfl_xor(ss, m);
  if (lane == 0) ssred[w] = ss;
#pragma unroll
  for (int nt = 0; nt < 4; ++nt) red[w * 4 + quad][nt * 16 + m16] = colp[nt];
  __syncthreads();
  if (tid < 64) {
    float s = 0.f;
#pragma unroll
    for (int t = 0; t < 16; ++t) s += red[t][tid];
    atomicAdd(&colsum[j0 + tid], (double)s);
  }
  if (tid == 0) {
    double v = (double)ssred[0] + ssred[1] + ssred[2] + ssred[3];
    atomicAdd(&ss_parts[blockIdx.x & 63], v);
  }
}

// ---------------------------------------------------------------------------
__global__ __launch_bounds__(256) void mu_k(
    const double* __restrict__ colsum, float* __restrict__ mu,
    double* __restrict__ summu2)
{
  __shared__ double wred[4];
  double local = 0.0;
  for (int j = threadIdx.x; j < NV; j += 256) {
    double m = colsum[j] * (1.0 / (double)NXP);
    mu[j] = (float)m;
    local += m * m;
  }
  int lane = threadIdx.x & 63, wave = threadIdx.x >> 6;
#pragma unroll
  for (int m = 32; m >= 1; m >>= 1) local += __shfl_xor(local, m);
  if (lane == 0) wred[wave] = local;
  __syncthreads();
  if (threadIdx.x == 0) *summu2 = wred[0] + wred[1] + wred[2] + wred[3];
}

// ---------------------------------------------------------------------------
// Pass 2 on bf16 fm: z_i = fm[i,:].mu ; sum z^2.
// ---------------------------------------------------------------------------
__global__ __launch_bounds__(256) void pass2_k(
    const u16* __restrict__ fm, const float* __restrict__ mu,
    double* __restrict__ sz_parts)
{
  __shared__ float mus[NV];
  for (int l = threadIdx.x; l < NV; l += 256) mus[l] = mu[l];
  __syncthreads();
  __shared__ double zb[4];
  int wave = threadIdx.x >> 6, lane = threadIdx.x & 63;
  int row = blockIdx.x * 4 + wave;
  const u16* frow = fm + (size_t)row * NV;
  float z = 0.f;
#pragma unroll
  for (int it = 0; it < 2; ++it) {
    int base = (lane + 64 * it) * 8;
    uint4 raw = *reinterpret_cast<const uint4*>(&frow[base]);
    const u16* v = reinterpret_cast<const u16*>(&raw);
#pragma unroll
    for (int k = 0; k < 8; ++k) z = fmaf(bf2f(v[k]), mus[base + k], z);
  }
#pragma unroll
  for (int m = 32; m >= 1; m >>= 1) z += __shfl_xor(z, m);
  if (lane == 0) zb[wave] = (double)z * (double)z;
  __syncthreads();
  if (threadIdx.x == 0)
    atomicAdd(&sz_parts[blockIdx.x & 63], zb[0] + zb[1] + zb[2] + zb[3]);
}

__global__ __launch_bounds__(64) void final_k(
    const double* __restrict__ ss_parts, const double* __restrict__ sz_parts,
    const double* __restrict__ summu2, float* __restrict__ out)
{
  int lane = threadIdx.x;
  double ss = ss_parts[lane], sz = sz_parts[lane];
#pragma unroll
  for (int m = 32; m >= 1; m >>= 1) { ss += __shfl_xor(ss, m); sz += __shfl_xor(sz, m); }
  if (lane == 0) {
    double smu2 = *summu2;
    const double nx = (double)NXP;
    double t1 = smu2 * nx / (nx - 1.0);
    double t2 = ss / (nx * (nx - 1.0));
    double um = t1 - t2;
    double uv = 4.0 * (sz / nx) - 4.0 * smu2 * smu2;
    out[0] = (float)(-(um / sqrt(uv + 1e-6)));
  }
}

// ---------------------------------------------------------------------------
extern "C" void kernel_launch(void* const* d_in, const int* in_sizes, int n_in,
                              void* d_out, int out_size, void* d_ws, size_t ws_size,
                              hipStream_t stream)
{
  (void)in_sizes; (void)n_in; (void)out_size; (void)ws_size;
  const float* XY = (const float*)d_in[0];
  const float* V  = (const float*)d_in[1];
  const float* dnW[6]; const float* dnb[6]; const float* anW[6]; const float* anb[6];
  for (int i = 0; i < 6; ++i) {
    dnW[i] = (const float*)d_in[2 + 2 * i];  dnb[i] = (const float*)d_in[3 + 2 * i];
    anW[i] = (const float*)d_in[14 + 2 * i]; anb[i] = (const float*)d_in[15 + 2 * i];
  }
  const float* p_eps  = (const float*)d_in[26];
  const float* p_sig  = (const float*)d_in[27];
  const float* p_sig0 = (const float*)d_in[28];
  const float* p_cst  = (const float*)d_in[29];

  char* base = (char*)d_ws;
  size_t off = 0;
  auto alloc = [&](size_t b) { size_t o = off; off += (b + 255) & ~(size_t)255; return o; };
  float* Xf    = (float*)(base + alloc((size_t)NROW * GD * 4));
  u16*   Xhi   = (u16*)  (base + alloc((size_t)NROW * 32 * 2));
  float* f_all = (float*)(base + alloc((size_t)NROW * FD * 4));
  float* g_all = (float*)(base + alloc((size_t)NROW * GD * 4));
  float* fn    = (float*)(base + alloc((size_t)NROW * 4));
  float* gn    = (float*)(base + alloc((size_t)NROW * 4));
  float* mu    = (float*)(base + alloc((size_t)NV * 4));
  size_t zoff = off;
  double* colsum   = (double*)(base + alloc(NV * 8));
  double* ss_parts = (double*)(base + alloc(64 * 8));
  double* sz_parts = (double*)(base + alloc(64 * 8));
  double* summu2   = (double*)(base + alloc(8));
  size_t zbytes = off - zoff;
  u16* Whi = (u16*)(base + alloc((size_t)12 * HP * HP * 2));
  u16* Wlo = (u16*)(base + alloc((size_t)12 * HP * HP * 2));
  u16* fhi = (u16*)(base + alloc((size_t)NROW * FKP * 2));
  u16* flo = (u16*)(base + alloc((size_t)NROW * FKP * 2));
  u16* ghi = (u16*)(base + alloc((size_t)NROW * GKP * 2));
  u16* glo = (u16*)(base + alloc((size_t)NROW * GKP * 2));
  u16* fm  = (u16*)(base + alloc((size_t)NXP * NV * 2));   // bf16 fm

  hipMemsetAsync(base + zoff, 0, zbytes, stream);

  dim3 blk(256);
  prep_x<<<NROW * 32 / 256, blk, 0, stream>>>(XY, V, Xhi, Xf);

  WAll wa;
  for (int i = 0; i < 6; ++i) {
    int K = (i == 0) ? GD : HD, M = (i == 5) ? FD : HD;
    int Kp = (i == 0) ? 32 : HP, Mp = (i == 5) ? 128 : HP;
    wa.d[i] = {dnW[i], Whi + (size_t)i * HP * HP, Wlo + (size_t)i * HP * HP, K, M, Kp, Mp};
  }
  for (int i = 0; i < 6; ++i) {
    int K = (i == 0) ? GD : HD, M = (i == 5) ? GD : HD;
    int Kp = (i == 0) ? 32 : HP, Mp = (i == 5) ? 64 : HP;
    wa.d[6 + i] = {anW[i], Whi + (size_t)(6 + i) * HP * HP, Wlo + (size_t)(6 + i) * HP * HP, K, M, Kp, Mp};
  }
  prep_w<<<dim3((HP * HP + 255) / 256, 12), blk, 0, stream>>>(wa);

  BiasAll bp;
  for (int i = 0; i < 6; ++i) { bp.b[i] = dnb[i]; bp.b[6 + i] = anb[i]; }

  const int nblk = (NROW + SAMP - 1) / SAMP;   // 694, last block overlaps (idempotent)
  mlp_fused<<<nblk, dim3(512), 0, stream>>>(Xhi, Xf, Whi, Wlo, bp, f_all, g_all);

  norms_k<<<NROW / 4, blk, 0, stream>>>(f_all, g_all, fn, gn);
  prep_fg<<<(int)(((size_t)NROW * 160 + 255) / 256), blk, 0, stream>>>(
      f_all, g_all, fhi, flo, ghi, glo);
  dist2_k<<<dim3(NXP / 64, NV / 64), blk, 0, stream>>>(
      fhi, flo, ghi, glo, fn, gn, p_eps, p_sig, p_sig0, p_cst,
      fm, colsum, ss_parts);
  mu_k<<<1, blk, 0, stream>>>(colsum, mu, summu2);
  pass2_k<<<NXP / 4, blk, 0, stream>>>(fm, mu, sz_parts);
  final_k<<<1, 64, 0, stream>>>(ss_parts, sz_parts, summu2, (float*)d_out);
}

// Round 15
// 724.360 us; speedup vs baseline: 1.6152x; 1.0965x over previous
//
#include <hip/hip_runtime.h>
#include <cstdint>

#define NROW 66560   // 2*NX + J rows through both MLPs
#define NXP  32768   // nx
#define NV   1024    // J
#define FD   100     // dn output dim
#define GD   28      // input / an output dim
#define HD   300     // hidden dim
#define HP   320     // padded hidden dim
#define SAMP 96      // samples per block (MLP)
#define NT   6       // sample tiles
#define ASTR 328     // LDS activation stride (u16)
#define FKP  128     // f padded K for dist MFMA
#define GKP  32      // g padded K

typedef unsigned short u16;
typedef __bf16 bf16x8 __attribute__((ext_vector_type(8)));
typedef float  f32x4  __attribute__((ext_vector_type(4)));

__device__ inline u16 f2bf(float x) {
  unsigned u = __builtin_bit_cast(unsigned, x);
  unsigned r = (u + 0x7FFF + ((u >> 16) & 1)) >> 16;
  return (u16)r;
}
__device__ inline float bf2f(u16 h) {
  unsigned u = ((unsigned)h) << 16;
  return __builtin_bit_cast(float, u);
}

// ---------------------------------------------------------------------------
// Prep: assemble [X;Y;V] rows -> single bf16 plane (K 28->32) + fp32 copy.
// ---------------------------------------------------------------------------
__global__ __launch_bounds__(256) void prep_x(
    const float* __restrict__ XY, const float* __restrict__ V,
    u16* __restrict__ Xhi, float* __restrict__ Xf)
{
  int gid = blockIdx.x * 256 + threadIdx.x;
  int row = gid >> 5, k = gid & 31;
  if (row >= NROW) return;
  float v = 0.f;
  if (k < GD) v = (row < 2 * NXP) ? XY[(size_t)row * GD + k]
                                  : V[(size_t)(row - 2 * NXP) * GD + k];
  Xhi[(size_t)row * 32 + k] = f2bf(v);
  if (k < GD) Xf[(size_t)row * GD + k] = v;
}

// ---------------------------------------------------------------------------
// Prep: transpose + split + zero-pad all 12 weight matrices. Wt[m][k] layout.
// ---------------------------------------------------------------------------
struct WDesc { const float* W; u16* hi; u16* lo; int K, M, Kpad, Mpad; };
struct WAll  { WDesc d[12]; };

__global__ __launch_bounds__(256) void prep_w(WAll wa)
{
  WDesc d = wa.d[blockIdx.y];
  int gid = blockIdx.x * 256 + threadIdx.x;
  if (gid >= d.Kpad * d.Mpad) return;
  int m = gid / d.Kpad, k = gid - m * d.Kpad;
  float v = (k < d.K && m < d.M) ? d.W[(size_t)k * d.M + m] : 0.f;
  u16 hi = f2bf(v);
  u16 lo = f2bf(v - bf2f(hi));
  d.hi[(size_t)m * d.Kpad + k] = hi;
  d.lo[(size_t)m * d.Kpad + k] = lo;
}

// ---------------------------------------------------------------------------
// Fused 12-layer MLP v11 (R14 + final spill fix + direct hi/lo output).
// 96 samp, 512 thr, 4 waves/SIMD, 63KB LDS -> 2 blocks/CU.
//  - mm6: B-frags in 3 groups of 2 (bh[2]) -> peak ~120 regs <= 128 budget
//  - final layers write fhi/flo, ghi/glo hi/lo bf16 planes DIRECTLY
//    (prep_fg kernel deleted; pad cols zeroed here)
// bf16x2: weights hi/lo split, activations single bf16.
// ---------------------------------------------------------------------------
struct BiasAll { const float* b[12]; };

template<int MT>
__device__ __forceinline__ void mm6(
    const u16* __restrict__ Wh, const u16* __restrict__ Wl,
    const u16* aH,
    f32x4 (&acc)[3][NT], int featbase, int m16, int quad)
{
#pragma unroll
  for (int mt = 0; mt < MT; ++mt)
#pragma unroll
    for (int nt = 0; nt < NT; ++nt) acc[mt][nt] = (f32x4)0.f;
#pragma unroll 2
  for (int ch = 0; ch < 10; ++ch) {
    const int k0 = ch * 32 + quad * 8;
    bf16x8 wh[MT], wl[MT];
#pragma unroll
    for (int mt = 0; mt < MT; ++mt) {
      size_t wo = (size_t)(featbase + mt * 16) * HP + k0;
      wh[mt] = *reinterpret_cast<const bf16x8*>(&Wh[wo]);
      wl[mt] = *reinterpret_cast<const bf16x8*>(&Wl[wo]);
    }
#pragma unroll
    for (int g = 0; g < 3; ++g) {
      bf16x8 bh[2];
#pragma unroll
      for (int n2 = 0; n2 < 2; ++n2)
        bh[n2] = *reinterpret_cast<const bf16x8*>(&aH[((g * 2 + n2) * 16 + m16) * ASTR + k0]);
#pragma unroll
      for (int mt = 0; mt < MT; ++mt)
#pragma unroll
        for (int n2 = 0; n2 < 2; ++n2) {
          acc[mt][g * 2 + n2] = __builtin_amdgcn_mfma_f32_16x16x32_bf16(wh[mt], bh[n2], acc[mt][g * 2 + n2], 0, 0, 0);
          acc[mt][g * 2 + n2] = __builtin_amdgcn_mfma_f32_16x16x32_bf16(wl[mt], bh[n2], acc[mt][g * 2 + n2], 0, 0, 0);
        }
    }
  }
}

// Layer 0/6: K=32, bf16x2, input single-bf16 plane.
template<int MT>
__device__ __forceinline__ void mm6_in(
    const u16* __restrict__ Wh, const u16* __restrict__ Wl,
    const u16* __restrict__ Xhi, int row0,
    f32x4 (&acc)[3][NT], int featbase, int m16, int quad)
{
#pragma unroll
  for (int mt = 0; mt < MT; ++mt)
#pragma unroll
    for (int nt = 0; nt < NT; ++nt) acc[mt][nt] = (f32x4)0.f;
  const int k0 = quad * 8;
  bf16x8 wh[MT], wl[MT];
#pragma unroll
  for (int mt = 0; mt < MT; ++mt) {
    size_t wo = (size_t)(featbase + mt * 16) * 32 + k0;
    wh[mt] = *reinterpret_cast<const bf16x8*>(&Wh[wo]);
    wl[mt] = *reinterpret_cast<const bf16x8*>(&Wl[wo]);
  }
#pragma unroll
  for (int g = 0; g < 3; ++g) {
    bf16x8 bh[2];
#pragma unroll
    for (int n2 = 0; n2 < 2; ++n2) {
      int samp = (g * 2 + n2) * 16 + m16;
      bh[n2] = *reinterpret_cast<const bf16x8*>(&Xhi[(size_t)(row0 + samp) * 32 + k0]);
    }
#pragma unroll
    for (int mt = 0; mt < MT; ++mt)
#pragma unroll
      for (int n2 = 0; n2 < 2; ++n2) {
        acc[mt][g * 2 + n2] = __builtin_amdgcn_mfma_f32_16x16x32_bf16(wh[mt], bh[n2], acc[mt][g * 2 + n2], 0, 0, 0);
        acc[mt][g * 2 + n2] = __builtin_amdgcn_mfma_f32_16x16x32_bf16(wl[mt], bh[n2], acc[mt][g * 2 + n2], 0, 0, 0);
      }
  }
}

template<int MT>
__device__ __forceinline__ void epi6(
    f32x4 (&acc)[3][NT], const float* __restrict__ bias,
    u16* aH, int ftile0, int m16, int quad)
{
#pragma unroll
  for (int mt = 0; mt < MT; ++mt) {
    int featb = ftile0 + mt * 16 + quad * 4;
#pragma unroll
    for (int nt = 0; nt < NT; ++nt) {
      int samp = nt * 16 + m16;
      ushort4 h4;
#pragma unroll
      for (int r = 0; r < 4; ++r) {
        int feat = featb + r;
        float x = acc[mt][nt][r] + (feat < HD ? bias[feat] : 0.f);
        x = fmaxf(x, 0.f);
        reinterpret_cast<u16*>(&h4)[r] = f2bf(x);
      }
      *reinterpret_cast<ushort4*>(&aH[samp * ASTR + featb]) = h4;
    }
  }
}

__global__ __launch_bounds__(512, 4) void mlp_fused(
    const u16* __restrict__ Xhi, const float* __restrict__ Xf,
    const u16* __restrict__ Whi, const u16* __restrict__ Wlo,
    BiasAll bp,
    u16* __restrict__ fhi, u16* __restrict__ flo,
    u16* __restrict__ ghi, u16* __restrict__ glo)
{
  __shared__ u16 aH[SAMP * ASTR];   // 62,976 B -> 2 blocks/CU
  const int tid  = threadIdx.x;
  const int wave = tid >> 6, lane = tid & 63;
  const int m16  = lane & 15, quad = lane >> 4;
  const int row0 = (blockIdx.x * SAMP + SAMP <= NROW) ? blockIdx.x * SAMP
                                                      : NROW - SAMP;  // overlap-safe
  const int ftile0 = (wave < 4) ? wave * 48 : 192 + (wave - 4) * 32;

  auto W = [&](int s) { return Whi + (size_t)s * HP * HP; };
  auto Lw = [&](int s) { return Wlo + (size_t)s * HP * HP; };

  f32x4 acc[3][NT];

  // ---- dn MLP ----
  if (wave < 4) mm6_in<3>(W(0), Lw(0), Xhi, row0, acc, ftile0 + m16, m16, quad);
  else          mm6_in<2>(W(0), Lw(0), Xhi, row0, acc, ftile0 + m16, m16, quad);
  if (wave < 4) epi6<3>(acc, bp.b[0], aH, ftile0, m16, quad);
  else          epi6<2>(acc, bp.b[0], aH, ftile0, m16, quad);
  __syncthreads();
#pragma unroll 1
  for (int s = 1; s <= 4; ++s) {
    if (wave < 4) mm6<3>(W(s), Lw(s), aH, acc, ftile0 + m16, m16, quad);
    else          mm6<2>(W(s), Lw(s), aH, acc, ftile0 + m16, m16, quad);
    __syncthreads();
    if (wave < 4) epi6<3>(acc, bp.b[s], aH, ftile0, m16, quad);
    else          epi6<2>(acc, bp.b[s], aH, ftile0, m16, quad);
    __syncthreads();
  }
  // layer 5: all 8 waves cover cols 0..127 (pad cols write zero)
  {
    mm6<1>(W(5), Lw(5), aH, acc, wave * 16 + m16, m16, quad);
    const float* b5 = bp.b[5];
    int c = wave * 16 + quad * 4;
#pragma unroll
    for (int nt = 0; nt < NT; ++nt) {
      int samp = nt * 16 + m16;
      ushort4 h4, l4;
#pragma unroll
      for (int r = 0; r < 4; ++r) {
        int feat = c + r;
        float x = (feat < FD) ? acc[0][nt][r] + b5[feat] : 0.f;
        u16 h = f2bf(x);
        reinterpret_cast<u16*>(&h4)[r] = h;
        reinterpret_cast<u16*>(&l4)[r] = f2bf(x - bf2f(h));
      }
      size_t o = (size_t)(row0 + samp) * FKP + c;
      *reinterpret_cast<ushort4*>(&fhi[o]) = h4;
      *reinterpret_cast<ushort4*>(&flo[o]) = l4;
    }
  }
  __syncthreads();   // layer-5 reads of aH complete before overwrite

  // ---- an MLP ----
  if (wave < 4) mm6_in<3>(W(6), Lw(6), Xhi, row0, acc, ftile0 + m16, m16, quad);
  else          mm6_in<2>(W(6), Lw(6), Xhi, row0, acc, ftile0 + m16, m16, quad);
  if (wave < 4) epi6<3>(acc, bp.b[6], aH, ftile0, m16, quad);
  else          epi6<2>(acc, bp.b[6], aH, ftile0, m16, quad);
  __syncthreads();
#pragma unroll 1
  for (int s = 7; s <= 10; ++s) {
    if (wave < 4) mm6<3>(W(s), Lw(s), aH, acc, ftile0 + m16, m16, quad);
    else          mm6<2>(W(s), Lw(s), aH, acc, ftile0 + m16, m16, quad);
    __syncthreads();
    if (wave < 4) epi6<3>(acc, bp.b[s], aH, ftile0, m16, quad);
    else          epi6<2>(acc, bp.b[s], aH, ftile0, m16, quad);
    __syncthreads();
  }
  // layer 11: waves 0-1 cover cols 0..31 (pad cols write zero)
  if (wave < 2) {
    mm6<1>(W(11), Lw(11), aH, acc, wave * 16 + m16, m16, quad);
    const float* b11 = bp.b[11];
    int c = wave * 16 + quad * 4;
#pragma unroll
    for (int nt = 0; nt < NT; ++nt) {
      int samp = nt * 16 + m16;
      ushort4 h4, l4;
#pragma unroll
      for (int r = 0; r < 4; ++r) {
        int feat = c + r;
        float x = 0.f;
        if (feat < GD)
          x = acc[0][nt][r] + b11[feat] + Xf[(size_t)(row0 + samp) * GD + feat];
        u16 h = f2bf(x);
        reinterpret_cast<u16*>(&h4)[r] = h;
        reinterpret_cast<u16*>(&l4)[r] = f2bf(x - bf2f(h));
      }
      size_t o = (size_t)(row0 + samp) * GKP + c;
      *reinterpret_cast<ushort4*>(&ghi[o]) = h4;
      *reinterpret_cast<ushort4*>(&glo[o]) = l4;
    }
  }
}

// ---------------------------------------------------------------------------
// Row squared-norms from hi/lo planes. One wave per row.
// ---------------------------------------------------------------------------
__global__ __launch_bounds__(256) void norms_k(
    const u16* __restrict__ fhi, const u16* __restrict__ flo,
    const u16* __restrict__ ghi, const u16* __restrict__ glo,
    float* __restrict__ fn, float* __restrict__ gn)
{
  int wave = threadIdx.x >> 6, lane = threadIdx.x & 63;
  int row = blockIdx.x * 4 + wave;
  const u16* fh = fhi + (size_t)row * FKP;
  const u16* fl = flo + (size_t)row * FKP;
  float a = bf2f(fh[lane]) + bf2f(fl[lane]);
  float s = a * a;
  float b = bf2f(fh[lane + 64]) + bf2f(fl[lane + 64]);
  s += b * b;
  float sg = 0.f;
  if (lane < GKP) {
    float t = bf2f(ghi[(size_t)row * GKP + lane]) + bf2f(glo[(size_t)row * GKP + lane]);
    sg = t * t;
  }
#pragma unroll
  for (int m = 32; m >= 1; m >>= 1) { s += __shfl_xor(s, m); sg += __shfl_xor(sg, m); }
  if (lane == 0) { fn[row] = s; gn[row] = sg; }
}

// ---------------------------------------------------------------------------
// Dist pass via MFMA. R15: V-side single bf16 (vl terms dropped):
// per nt: S += xh*vh + xl*vh  (X/Y keep hi/lo). 64 f-MFMAs + 16 g-MFMAs/wave.
// ---------------------------------------------------------------------------
__global__ __launch_bounds__(256) void dist2_k(
    const u16* __restrict__ fhi, const u16* __restrict__ flo,
    const u16* __restrict__ ghi, const u16* __restrict__ glo,
    const float* __restrict__ fn, const float* __restrict__ gn,
    const float* __restrict__ p_eps, const float* __restrict__ p_sig,
    const float* __restrict__ p_sig0, const float* __restrict__ p_cst,
    u16* __restrict__ fm, double* __restrict__ colsum,
    double* __restrict__ ss_parts)
{
  __shared__ float fnX[64], fnY[64], fnV[64], gnX[64], gnY[64], gnV[64];
  __shared__ float red[16][66];
  __shared__ float ssred[4];
  const int tid = threadIdx.x;
  const int w = tid >> 6, lane = tid & 63;
  const int m16 = lane & 15, quad = lane >> 4;
  const int i0 = blockIdx.x * 64, j0 = blockIdx.y * 64;

  if (tid < 64) {
    fnX[tid] = fn[i0 + tid]; fnY[tid] = fn[NXP + i0 + tid]; fnV[tid] = fn[2 * NXP + j0 + tid];
    gnX[tid] = gn[i0 + tid]; gnY[tid] = gn[NXP + i0 + tid]; gnV[tid] = gn[2 * NXP + j0 + tid];
  }

  f32x4 axf[4], ayf[4], axg[4], ayg[4];
#pragma unroll
  for (int nt = 0; nt < 4; ++nt) {
    axf[nt] = (f32x4)0.f; ayf[nt] = (f32x4)0.f;
    axg[nt] = (f32x4)0.f; ayg[nt] = (f32x4)0.f;
  }

  const u16* Xh = fhi + (size_t)(i0 + w * 16 + m16) * FKP;
  const u16* Xl = flo + (size_t)(i0 + w * 16 + m16) * FKP;
  const u16* Yh = fhi + (size_t)(NXP + i0 + w * 16 + m16) * FKP;
  const u16* Yl = flo + (size_t)(NXP + i0 + w * 16 + m16) * FKP;
  const u16* Vh = fhi + (size_t)(2 * NXP + j0) * FKP;
#pragma unroll 1
  for (int ch = 0; ch < 4; ++ch) {
    const int k = ch * 32 + quad * 8;
    bf16x8 xh = *reinterpret_cast<const bf16x8*>(&Xh[k]);
    bf16x8 xl = *reinterpret_cast<const bf16x8*>(&Xl[k]);
    bf16x8 yh = *reinterpret_cast<const bf16x8*>(&Yh[k]);
    bf16x8 yl = *reinterpret_cast<const bf16x8*>(&Yl[k]);
    bf16x8 vh[4];
#pragma unroll
    for (int nt = 0; nt < 4; ++nt)
      vh[nt] = *reinterpret_cast<const bf16x8*>(&Vh[(size_t)(nt * 16 + m16) * FKP + k]);
    __builtin_amdgcn_sched_barrier(0);
#pragma unroll
    for (int nt = 0; nt < 4; ++nt) {
      axf[nt] = __builtin_amdgcn_mfma_f32_16x16x32_bf16(xh, vh[nt], axf[nt], 0, 0, 0);
      axf[nt] = __builtin_amdgcn_mfma_f32_16x16x32_bf16(xl, vh[nt], axf[nt], 0, 0, 0);
      ayf[nt] = __builtin_amdgcn_mfma_f32_16x16x32_bf16(yh, vh[nt], ayf[nt], 0, 0, 0);
      ayf[nt] = __builtin_amdgcn_mfma_f32_16x16x32_bf16(yl, vh[nt], ayf[nt], 0, 0, 0);
    }
    __builtin_amdgcn_sched_barrier(0);
  }
  {
    const int k = quad * 8;
    bf16x8 xh = *reinterpret_cast<const bf16x8*>(&ghi[(size_t)(i0 + w * 16 + m16) * GKP + k]);
    bf16x8 xl = *reinterpret_cast<const bf16x8*>(&glo[(size_t)(i0 + w * 16 + m16) * GKP + k]);
    bf16x8 yh = *reinterpret_cast<const bf16x8*>(&ghi[(size_t)(NXP + i0 + w * 16 + m16) * GKP + k]);
    bf16x8 yl = *reinterpret_cast<const bf16x8*>(&glo[(size_t)(NXP + i0 + w * 16 + m16) * GKP + k]);
    bf16x8 vh[4];
#pragma unroll
    for (int nt = 0; nt < 4; ++nt)
      vh[nt] = *reinterpret_cast<const bf16x8*>(&ghi[(size_t)(2 * NXP + j0 + nt * 16 + m16) * GKP + k]);
    __builtin_amdgcn_sched_barrier(0);
#pragma unroll
    for (int nt = 0; nt < 4; ++nt) {
      axg[nt] = __builtin_amdgcn_mfma_f32_16x16x32_bf16(xh, vh[nt], axg[nt], 0, 0, 0);
      axg[nt] = __builtin_amdgcn_mfma_f32_16x16x32_bf16(xl, vh[nt], axg[nt], 0, 0, 0);
      ayg[nt] = __builtin_amdgcn_mfma_f32_16x16x32_bf16(yh, vh[nt], ayg[nt], 0, 0, 0);
      ayg[nt] = __builtin_amdgcn_mfma_f32_16x16x32_bf16(yl, vh[nt], ayg[nt], 0, 0, 0);
    }
    __builtin_amdgcn_sched_barrier(0);
  }
  __syncthreads();   // norms ready

  float ep  = 1.f / (1.f + __expf(-p_eps[0]));
  float sg  = p_sig[0] * p_sig[0];
  float sg0 = p_sig0[0] * p_sig0[0];
  float cst = p_cst[0];
  float nis = -1.f / sg, nis0 = -1.f / sg0;
  float omep = 1.f - ep;
  float ss = 0.f;
  float colp[4] = {0.f, 0.f, 0.f, 0.f};
#pragma unroll
  for (int nt = 0; nt < 4; ++nt) {
    float fv = fnV[nt * 16 + m16], gv = gnV[nt * 16 + m16];
#pragma unroll
    for (int r = 0; r < 4; ++r) {
      int il = w * 16 + quad * 4 + r;
      float fx = fnX[il], fy = fnY[il], gx = gnX[il], gy = gnY[il];
      float dxf = fmaxf(fx + fv - 2.f * axf[nt][r], 0.f);
      float dxg = fmaxf(gx + gv - 2.f * axg[nt][r], 0.f);
      float dyf = fmaxf(fy + fv - 2.f * ayf[nt][r], 0.f);
      float dyg = fmaxf(gy + gv - 2.f * ayg[nt][r], 0.f);
      float kx = cst * (omep * __expf(dxf * nis0) + ep) * __expf(dxg * nis);
      float ky = cst * (omep * __expf(dyf * nis0) + ep) * __expf(dyg * nis);
      float fmv = (kx - ky) * 0.03125f;
      fm[(size_t)(i0 + il) * NV + j0 + nt * 16 + m16] = f2bf(fmv);
      ss = fmaf(fmv, fmv, ss);
      colp[nt] += fmv;
    }
  }
#pragma unroll
  for (int m = 32; m >= 1; m >>= 1) ss += __shfl_xor(ss, m);
  if (lane == 0) ssred[w] = ss;
#pragma unroll
  for (int nt = 0; nt < 4; ++nt) red[w * 4 + quad][nt * 16 + m16] = colp[nt];
  __syncthreads();
  if (tid < 64) {
    float s = 0.f;
#pragma unroll
    for (int t = 0; t < 16; ++t) s += red[t][tid];
    atomicAdd(&colsum[j0 + tid], (double)s);
  }
  if (tid == 0) {
    double v = (double)ssred[0] + ssred[1] + ssred[2] + ssred[3];
    atomicAdd(&ss_parts[blockIdx.x & 63], v);
  }
}

// ---------------------------------------------------------------------------
__global__ __launch_bounds__(256) void mu_k(
    const double* __restrict__ colsum, float* __restrict__ mu,
    double* __restrict__ summu2)
{
  __shared__ double wred[4];
  double local = 0.0;
  for (int j = threadIdx.x; j < NV; j += 256) {
    double m = colsum[j] * (1.0 / (double)NXP);
    mu[j] = (float)m;
    local += m * m;
  }
  int lane = threadIdx.x & 63, wave = threadIdx.x >> 6;
#pragma unroll
  for (int m = 32; m >= 1; m >>= 1) local += __shfl_xor(local, m);
  if (lane == 0) wred[wave] = local;
  __syncthreads();
  if (threadIdx.x == 0) *summu2 = wred[0] + wred[1] + wred[2] + wred[3];
}

// ---------------------------------------------------------------------------
// Pass 2 on bf16 fm: z_i = fm[i,:].mu ; sum z^2.
// ---------------------------------------------------------------------------
__global__ __launch_bounds__(256) void pass2_k(
    const u16* __restrict__ fm, const float* __restrict__ mu,
    double* __restrict__ sz_parts)
{
  __shared__ float mus[NV];
  for (int l = threadIdx.x; l < NV; l += 256) mus[l] = mu[l];
  __syncthreads();
  __shared__ double zb[4];
  int wave = threadIdx.x >> 6, lane = threadIdx.x & 63;
  int row = blockIdx.x * 4 + wave;
  const u16* frow = fm + (size_t)row * NV;
  float z = 0.f;
#pragma unroll
  for (int it = 0; it < 2; ++it) {
    int base = (lane + 64 * it) * 8;
    uint4 raw = *reinterpret_cast<const uint4*>(&frow[base]);
    const u16* v = reinterpret_cast<const u16*>(&raw);
#pragma unroll
    for (int k = 0; k < 8; ++k) z = fmaf(bf2f(v[k]), mus[base + k], z);
  }
#pragma unroll
  for (int m = 32; m >= 1; m >>= 1) z += __shfl_xor(z, m);
  if (lane == 0) zb[wave] = (double)z * (double)z;
  __syncthreads();
  if (threadIdx.x == 0)
    atomicAdd(&sz_parts[blockIdx.x & 63], zb[0] + zb[1] + zb[2] + zb[3]);
}

__global__ __launch_bounds__(64) void final_k(
    const double* __restrict__ ss_parts, const double* __restrict__ sz_parts,
    const double* __restrict__ summu2, float* __restrict__ out)
{
  int lane = threadIdx.x;
  double ss = ss_parts[lane], sz = sz_parts[lane];
#pragma unroll
  for (int m = 32; m >= 1; m >>= 1) { ss += __shfl_xor(ss, m); sz += __shfl_xor(sz, m); }
  if (lane == 0) {
    double smu2 = *summu2;
    const double nx = (double)NXP;
    double t1 = smu2 * nx / (nx - 1.0);
    double t2 = ss / (nx * (nx - 1.0));
    double um = t1 - t2;
    double uv = 4.0 * (sz / nx) - 4.0 * smu2 * smu2;
    out[0] = (float)(-(um / sqrt(uv + 1e-6)));
  }
}

// ---------------------------------------------------------------------------
extern "C" void kernel_launch(void* const* d_in, const int* in_sizes, int n_in,
                              void* d_out, int out_size, void* d_ws, size_t ws_size,
                              hipStream_t stream)
{
  (void)in_sizes; (void)n_in; (void)out_size; (void)ws_size;
  const float* XY = (const float*)d_in[0];
  const float* V  = (const float*)d_in[1];
  const float* dnW[6]; const float* dnb[6]; const float* anW[6]; const float* anb[6];
  for (int i = 0; i < 6; ++i) {
    dnW[i] = (const float*)d_in[2 + 2 * i];  dnb[i] = (const float*)d_in[3 + 2 * i];
    anW[i] = (const float*)d_in[14 + 2 * i]; anb[i] = (const float*)d_in[15 + 2 * i];
  }
  const float* p_eps  = (const float*)d_in[26];
  const float* p_sig  = (const float*)d_in[27];
  const float* p_sig0 = (const float*)d_in[28];
  const float* p_cst  = (const float*)d_in[29];

  char* base = (char*)d_ws;
  size_t off = 0;
  auto alloc = [&](size_t b) { size_t o = off; off += (b + 255) & ~(size_t)255; return o; };
  float* Xf    = (float*)(base + alloc((size_t)NROW * GD * 4));
  u16*   Xhi   = (u16*)  (base + alloc((size_t)NROW * 32 * 2));
  float* fn    = (float*)(base + alloc((size_t)NROW * 4));
  float* gn    = (float*)(base + alloc((size_t)NROW * 4));
  float* mu    = (float*)(base + alloc((size_t)NV * 4));
  size_t zoff = off;
  double* colsum   = (double*)(base + alloc(NV * 8));
  double* ss_parts = (double*)(base + alloc(64 * 8));
  double* sz_parts = (double*)(base + alloc(64 * 8));
  double* summu2   = (double*)(base + alloc(8));
  size_t zbytes = off - zoff;
  u16* Whi = (u16*)(base + alloc((size_t)12 * HP * HP * 2));
  u16* Wlo = (u16*)(base + alloc((size_t)12 * HP * HP * 2));
  u16* fhi = (u16*)(base + alloc((size_t)NROW * FKP * 2));
  u16* flo = (u16*)(base + alloc((size_t)NROW * FKP * 2));
  u16* ghi = (u16*)(base + alloc((size_t)NROW * GKP * 2));
  u16* glo = (u16*)(base + alloc((size_t)NROW * GKP * 2));
  u16* fm  = (u16*)(base + alloc((size_t)NXP * NV * 2));   // bf16 fm

  hipMemsetAsync(base + zoff, 0, zbytes, stream);

  dim3 blk(256);
  prep_x<<<NROW * 32 / 256, blk, 0, stream>>>(XY, V, Xhi, Xf);

  WAll wa;
  for (int i = 0; i < 6; ++i) {
    int K = (i == 0) ? GD : HD, M = (i == 5) ? FD : HD;
    int Kp = (i == 0) ? 32 : HP, Mp = (i == 5) ? 128 : HP;
    wa.d[i] = {dnW[i], Whi + (size_t)i * HP * HP, Wlo + (size_t)i * HP * HP, K, M, Kp, Mp};
  }
  for (int i = 0; i < 6; ++i) {
    int K = (i == 0) ? GD : HD, M = (i == 5) ? GD : HD;
    int Kp = (i == 0) ? 32 : HP, Mp = (i == 5) ? 64 : HP;
    wa.d[6 + i] = {anW[i], Whi + (size_t)(6 + i) * HP * HP, Wlo + (size_t)(6 + i) * HP * HP, K, M, Kp, Mp};
  }
  prep_w<<<dim3((HP * HP + 255) / 256, 12), blk, 0, stream>>>(wa);

  BiasAll bp;
  for (int i = 0; i < 6; ++i) { bp.b[i] = dnb[i]; bp.b[6 + i] = anb[i]; }

  const int nblk = (NROW + SAMP - 1) / SAMP;   // 694, last block overlaps (idempotent)
  mlp_fused<<<nblk, dim3(512), 0, stream>>>(Xhi, Xf, Whi, Wlo, bp, fhi, flo, ghi, glo);

  norms_k<<<NROW / 4, blk, 0, stream>>>(fhi, flo, ghi, glo, fn, gn);
  dist2_k<<<dim3(NXP / 64, NV / 64), blk, 0, stream>>>(
      fhi, flo, ghi, glo, fn, gn, p_eps, p_sig, p_sig0, p_cst,
      fm, colsum, ss_parts);
  mu_k<<<1, blk, 0, stream>>>(colsum, mu, summu2);
  pass2_k<<<NXP / 4, blk, 0, stream>>>(fm, mu, sz_parts);
  final_k<<<1, 64, 0, stream>>>(ss_parts, sz_parts, summu2, (float*)d_out);
}